// Round 20
// baseline (589.363 us; speedup 1.0000x reference)
//
#include <hip/hip_runtime.h>

#define NPTS   8192
#define NBATCH 16
#define NGROUP 512
#define GSIZE  32
#define BIGF   1e10f
#define KBLK   7          // consumer blocks per batch (r19 proven)

typedef unsigned long long u64;

// DPP max on a packed u64 key (round-7 proven).
template <int CTRL>
__device__ __forceinline__ u64 dpp_max_u64(u64 k) {
    const unsigned lo  = (unsigned)k;
    const unsigned hi  = (unsigned)(k >> 32);
    const unsigned slo = (unsigned)__builtin_amdgcn_update_dpp(0, (int)lo, CTRL, 0xF, 0xF, true);
    const unsigned shi = (unsigned)__builtin_amdgcn_update_dpp(0, (int)hi, CTRL, 0xF, 0xF, true);
    const u64 s = ((u64)shi << 32) | slo;
    return s > k ? s : k;
}

__device__ __forceinline__ u64 umax64(u64 a, u64 b) { return a > b ? a : b; }

// wave-uniform 64-bit readlane (SALU path, no LDS pipe)
__device__ __forceinline__ u64 rdlane64(u64 v, int l) {
    const unsigned lo = (unsigned)__builtin_amdgcn_readlane((int)(unsigned)v, l);
    const unsigned hi = (unsigned)__builtin_amdgcn_readlane((int)(unsigned)(v >> 32), l);
    return ((u64)hi << 32) | lo;
}

// ---------------------------------------------------------------------------
// knn scan for ONE query — r11 machinery (u64 keys = f64 bit order, readlane
// broadcasts, 2 points/lane/iter, lane-distributed sorted top-32) reading the
// block's LDS copy of the batch xyz. Bit-identical keys/order to r11.
// ---------------------------------------------------------------------------
__device__ __forceinline__ void knn_one(const float* __restrict__ base,
                                        const float4* sp,
                                        float* __restrict__ out,
                                        const int q, const int r, const int lane) {
    const float4 Q = sp[r];
    const float qxf = Q.x, qyf = Q.y, qzf = Q.z;
    const double qx = (double)qxf, qy = (double)qyf, qz = (double)qzf;

    const u64 INFB = 0x7ff0000000000000ull;
    u64 vk = INFB;  int vi = 0x7fffffff;
    u64 tauk = INFB;

    for (int i = 0; i < NPTS / 128; ++i) {
        const int p0 = i * 128 + lane;
        const float4 T0 = sp[p0];
        const float4 T1 = sp[p0 + 64];

        const double dx0 = qx - (double)T0.x;
        const double dy0 = qy - (double)T0.y;
        const double dz0 = qz - (double)T0.z;
        const u64 kd0 = __double_as_longlong(dx0 * dx0 + dy0 * dy0 + dz0 * dz0);
        const double dx1 = qx - (double)T1.x;
        const double dy1 = qy - (double)T1.y;
        const double dz1 = qz - (double)T1.z;
        const u64 kd1 = __double_as_longlong(dx1 * dx1 + dy1 * dy1 + dz1 * dz1);

        u64 m0 = __ballot(kd0 < tauk);
        const u64 m1pre = __ballot(kd1 < tauk);

        if (m0 | m1pre) {
            while (m0) {
                const int l = __ffsll(m0) - 1;
                m0 &= m0 - 1;
                const u64 xk = rdlane64(kd0, l);
                const int xi = i * 128 + l;
                const u64 pk = __shfl_up(vk, 1);
                const int pv = __shfl_up(vi, 1);
                const bool ltp = (lane > 0) && (xk < pk);
                const bool ltc = xk < vk;
                vk = ltp ? pk : (ltc ? xk : vk);
                vi = ltp ? pv : (ltc ? xi : vi);
            }
            tauk = rdlane64(vk, 31);
            u64 m1 = m1pre;
            while (m1) {
                const int l = __ffsll(m1) - 1;
                m1 &= m1 - 1;
                const u64 xk = rdlane64(kd1, l);
                if (xk < tauk) {
                    const int xi = i * 128 + 64 + l;
                    const u64 pk = __shfl_up(vk, 1);
                    const int pv = __shfl_up(vi, 1);
                    const bool ltp = (lane > 0) && (xk < pk);
                    const bool ltc = xk < vk;
                    vk = ltp ? pk : (ltc ? xk : vk);
                    vi = ltp ? pv : (ltc ? xi : vi);
                }
            }
            tauk = rdlane64(vk, 31);
        }
    }

    const size_t NBH = (size_t)NBATCH * NGROUP * GSIZE * 6;
    const size_t CEN = (size_t)NBATCH * NGROUP * 6;

    if (lane == 0) {
#pragma unroll
        for (int c = 0; c < 6; ++c)
            out[NBH + (size_t)q * 6 + c] = base[r * 6 + c];
    }
    if (lane < GSIZE) {
        const int n = vi;
        out[NBH + CEN + (size_t)q * GSIZE + lane] = (float)n;

        const float* np_ = base + (size_t)n * 6;
        const size_t o = ((size_t)q * GSIZE + lane) * 6;
        out[o + 0] = __fsub_rn(np_[0], qxf);
        out[o + 1] = __fsub_rn(np_[1], qyf);
        out[o + 2] = __fsub_rn(np_[2], qzf);
        out[o + 3] = np_[3];
        out[o + 4] = np_[4];
        out[o + 5] = np_[5];
    }
}

// ---------------------------------------------------------------------------
// Fused producer/consumer — r19 skeleton, ROUND-20: batched publication.
// The fused fps ran 2710 cyc/iter vs 2550 standalone; the +160cy/iter is the
// pre-barrier vmcnt(0) draining a per-iter agent store whose line is polled
// from other XCDs (must reach L3). Fix: lrep[k] in LDS every iter (cheap
// lgkm drain), flush groups of 8 via relaxed atomic stores every 8th iter ->
// one global drain per 8 barriers. Consumers wait <=7 extra iters (hidden by
// 56-slot overprovision); tail unchanged (group 63 publishes at k=511).
// ---------------------------------------------------------------------------
__global__ __launch_bounds__(512) void fused_kernel(const float* __restrict__ pc,
                                                    int* __restrict__ rep,
                                                    float* __restrict__ out) {
    const int bid  = blockIdx.x;
    const int t    = threadIdx.x;
    const int lane = t & 63;
    const int w    = t >> 6;

    __shared__ float4 sp[NPTS];                      // 128 KB
    __shared__ __align__(16) u64 keys[2][8];

    if (bid < NBATCH) {
        // ---------------- FPS producer (r11 body + batched publish) ---------
        const int b = bid;
        const float* base = pc + (size_t)b * NPTS * 6;
        __shared__ int lrep[NGROUP];                 // 2 KB

        float px[16], py[16], pz[16], dmin[16];
#pragma unroll
        for (int j = 0; j < 16; ++j) {
            const int p = t * 16 + j;
            const float x = base[p * 6 + 0];
            const float y = base[p * 6 + 1];
            const float z = base[p * 6 + 2];
            px[j] = x; py[j] = y; pz[j] = z;
            sp[p] = make_float4(x, y, z, 0.0f);
            dmin[j] = BIGF;
        }
        __syncthreads();

        int last = 0;
        for (int k = 0; k < NGROUP; ++k) {
            if (t == 0) {
                lrep[k] = last;                      // LDS: cheap drain
                if ((k & 7) == 7 || k == NGROUP - 1) {
                    const int k0 = k & ~7;           // flush group of 8
#pragma unroll
                    for (int jj = 0; jj < 8; ++jj)
                        __hip_atomic_store(rep + b * NGROUP + k0 + jj, lrep[k0 + jj],
                                           __ATOMIC_RELAXED, __HIP_MEMORY_SCOPE_AGENT);
                }
            }
            if (k == NGROUP - 1) break;

            const float4 L = sp[last];               // one ds_read_b128, broadcast

            float bv = -1.0f;
            int   bi = 0;
#pragma unroll
            for (int j = 0; j < 16; ++j) {
                const float dx = __fsub_rn(px[j], L.x);
                const float dy = __fsub_rn(py[j], L.y);
                const float dz = __fsub_rn(pz[j], L.z);
                // ((dx^2 + dy^2) + dz^2), no FMA -> matches numpy fp32 (verified)
                const float d = __fadd_rn(__fadd_rn(__fmul_rn(dx, dx),
                                                    __fmul_rn(dy, dy)),
                                          __fmul_rn(dz, dz));
                const float dm = fminf(dmin[j], d);
                dmin[j] = dm;
                if (dm > bv) { bv = dm; bi = t * 16 + j; }   // strict > keeps lowest idx
            }

            u64 key = ((u64)__float_as_uint(bv) << 13) | (unsigned)(8191 - bi);
            key = dpp_max_u64<0x111>(key);   // row_shr:1
            key = dpp_max_u64<0x112>(key);   // row_shr:2
            key = dpp_max_u64<0x114>(key);   // row_shr:4
            key = dpp_max_u64<0x118>(key);   // row_shr:8
            key = dpp_max_u64<0x142>(key);   // row_bcast:15
            key = dpp_max_u64<0x143>(key);   // row_bcast:31 -> lane 63 = wave max

            const int buf = k & 1;                   // parity dbuf -> 1 barrier/iter
            if (lane == 63) keys[buf][w] = key;
            __syncthreads();

            const ulonglong2* kp = (const ulonglong2*)keys[buf];   // 4x ds_read_b128
            const ulonglong2 k0 = kp[0], k1 = kp[1], k2 = kp[2], k3 = kp[3];
            const u64 best = umax64(umax64(umax64(k0.x, k0.y), umax64(k1.x, k1.y)),
                                    umax64(umax64(k2.x, k2.y), umax64(k3.x, k3.y)));
            last = 8191 - (int)(best & 0x1FFFull);
        }
    } else {
        // ---------------- KNN consumers -------------------------------------
        const int kb = bid - NBATCH;                 // 0..NBATCH*KBLK-1
        const int b  = kb / KBLK;                    // batch
        const int j  = kb % KBLK;                    // block-in-batch
        const int m0 = j * 8 + w;                    // wave's first query
        const int stride = KBLK * 8;                 // 56 wave-slots per batch

        const float* base = pc + (size_t)b * NPTS * 6;

        // stage the whole batch's xyz into this block's LDS (idle time:
        // happens before fps publishes anything)
#pragma unroll
        for (int jj = 0; jj < NPTS / 512; ++jj) {
            const int p = jj * 512 + t;
            sp[p] = make_float4(base[p * 6 + 0], base[p * 6 + 1],
                                base[p * 6 + 2], 0.0f);
        }
        __syncthreads();

        for (int m = m0; m < NGROUP; m += stride) {
            const int q = b * NGROUP + m;
            int rv;
            for (;;) {
                rv = __hip_atomic_load(rep + q, __ATOMIC_RELAXED,
                                       __HIP_MEMORY_SCOPE_AGENT);
                if (rv >= 0) break;
                __builtin_amdgcn_s_sleep(127);
            }
            knn_one(base, sp, out, q, rv, lane);
        }
    }
}

extern "C" void kernel_launch(void* const* d_in, const int* in_sizes, int n_in,
                              void* d_out, int out_size, void* d_ws, size_t ws_size,
                              hipStream_t stream) {
    const float* pc  = (const float*)d_in[0];
    float*       out = (float*)d_out;
    int*         rep = (int*)d_ws;                   // 32 KB

    // rep = -1 sentinels (0xFF bytes) — stream op, graph-capture-safe
    hipMemsetAsync(rep, 0xFF, (size_t)NBATCH * NGROUP * sizeof(int), stream);

    fused_kernel<<<NBATCH + NBATCH * KBLK, 512, 0, stream>>>(pc, rep, out);
}

// Round 21
// 580.032 us; speedup vs baseline: 1.0161x; 1.0161x over previous
//
#include <hip/hip_runtime.h>

#define NPTS   8192
#define NBATCH 16
#define NGROUP 512
#define GSIZE  32
#define BIGF   1e10f
#define KBLK   7          // consumer blocks per batch (r19 proven)

typedef unsigned long long u64;

// DPP max on a packed u64 key (round-7 proven).
template <int CTRL>
__device__ __forceinline__ u64 dpp_max_u64(u64 k) {
    const unsigned lo  = (unsigned)k;
    const unsigned hi  = (unsigned)(k >> 32);
    const unsigned slo = (unsigned)__builtin_amdgcn_update_dpp(0, (int)lo, CTRL, 0xF, 0xF, true);
    const unsigned shi = (unsigned)__builtin_amdgcn_update_dpp(0, (int)hi, CTRL, 0xF, 0xF, true);
    const u64 s = ((u64)shi << 32) | slo;
    return s > k ? s : k;
}

__device__ __forceinline__ u64 umax64(u64 a, u64 b) { return a > b ? a : b; }

// wave-uniform 64-bit readlane (SALU path, no LDS pipe)
__device__ __forceinline__ u64 rdlane64(u64 v, int l) {
    const unsigned lo = (unsigned)__builtin_amdgcn_readlane((int)(unsigned)v, l);
    const unsigned hi = (unsigned)__builtin_amdgcn_readlane((int)(unsigned)(v >> 32), l);
    return ((u64)hi << 32) | lo;
}

// ---------------------------------------------------------------------------
// knn scan for ONE query — r11 machinery (u64 keys = f64 bit order, readlane
// broadcasts, 2 points/lane/iter, lane-distributed sorted top-32) reading the
// block's LDS copy of the batch xyz. Bit-identical keys/order to r11.
// ---------------------------------------------------------------------------
__device__ __forceinline__ void knn_one(const float* __restrict__ base,
                                        const float4* sp,
                                        float* __restrict__ out,
                                        const int q, const int r, const int lane) {
    const float4 Q = sp[r];
    const float qxf = Q.x, qyf = Q.y, qzf = Q.z;
    const double qx = (double)qxf, qy = (double)qyf, qz = (double)qzf;

    const u64 INFB = 0x7ff0000000000000ull;
    u64 vk = INFB;  int vi = 0x7fffffff;
    u64 tauk = INFB;

    for (int i = 0; i < NPTS / 128; ++i) {
        const int p0 = i * 128 + lane;
        const float4 T0 = sp[p0];
        const float4 T1 = sp[p0 + 64];

        const double dx0 = qx - (double)T0.x;
        const double dy0 = qy - (double)T0.y;
        const double dz0 = qz - (double)T0.z;
        const u64 kd0 = __double_as_longlong(dx0 * dx0 + dy0 * dy0 + dz0 * dz0);
        const double dx1 = qx - (double)T1.x;
        const double dy1 = qy - (double)T1.y;
        const double dz1 = qz - (double)T1.z;
        const u64 kd1 = __double_as_longlong(dx1 * dx1 + dy1 * dy1 + dz1 * dz1);

        u64 m0 = __ballot(kd0 < tauk);
        const u64 m1pre = __ballot(kd1 < tauk);

        if (m0 | m1pre) {
            while (m0) {
                const int l = __ffsll(m0) - 1;
                m0 &= m0 - 1;
                const u64 xk = rdlane64(kd0, l);
                const int xi = i * 128 + l;
                const u64 pk = __shfl_up(vk, 1);
                const int pv = __shfl_up(vi, 1);
                const bool ltp = (lane > 0) && (xk < pk);
                const bool ltc = xk < vk;
                vk = ltp ? pk : (ltc ? xk : vk);
                vi = ltp ? pv : (ltc ? xi : vi);
            }
            tauk = rdlane64(vk, 31);
            u64 m1 = m1pre;
            while (m1) {
                const int l = __ffsll(m1) - 1;
                m1 &= m1 - 1;
                const u64 xk = rdlane64(kd1, l);
                if (xk < tauk) {
                    const int xi = i * 128 + 64 + l;
                    const u64 pk = __shfl_up(vk, 1);
                    const int pv = __shfl_up(vi, 1);
                    const bool ltp = (lane > 0) && (xk < pk);
                    const bool ltc = xk < vk;
                    vk = ltp ? pk : (ltc ? xk : vk);
                    vi = ltp ? pv : (ltc ? xi : vi);
                }
            }
            tauk = rdlane64(vk, 31);
        }
    }

    const size_t NBH = (size_t)NBATCH * NGROUP * GSIZE * 6;
    const size_t CEN = (size_t)NBATCH * NGROUP * 6;

    if (lane == 0) {
#pragma unroll
        for (int c = 0; c < 6; ++c)
            out[NBH + (size_t)q * 6 + c] = base[r * 6 + c];
    }
    if (lane < GSIZE) {
        const int n = vi;
        out[NBH + CEN + (size_t)q * GSIZE + lane] = (float)n;

        const float* np_ = base + (size_t)n * 6;
        const size_t o = ((size_t)q * GSIZE + lane) * 6;
        out[o + 0] = __fsub_rn(np_[0], qxf);
        out[o + 1] = __fsub_rn(np_[1], qyf);
        out[o + 2] = __fsub_rn(np_[2], qzf);
        out[o + 3] = np_[3];
        out[o + 4] = np_[4];
        out[o + 5] = np_[5];
    }
}

// ---------------------------------------------------------------------------
// Fused producer/consumer — r19 skeleton (572us best; r20's batched publish
// regressed and is reverted). ROUND-21: XCD-CO-LOCATED PLACEMENT.
// gfx950 maps blockIdx%8 -> XCD. Producer for batch b is block bid=b
// (XCD b%8). Consumers for batch b are now ONLY at bids ≡ b (mod 8):
// bid>=16, x=bid&7, slot=(bid>>3)-2 in 0..13, b=x+8*(slot/7), j=slot%7.
// The whole produce->store->poll->consume loop for a batch then lives in
// one XCD's L2 — testing whether cross-XCD propagation of the rep line is
// the residual ~34us tax (read-BW r16, acquire r17, poll-rate r18, batching
// r20 all falsified). Placement is a heuristic: correctness independent.
// ---------------------------------------------------------------------------
__global__ __launch_bounds__(512) void fused_kernel(const float* __restrict__ pc,
                                                    int* __restrict__ rep,
                                                    float* __restrict__ out) {
    const int bid  = blockIdx.x;
    const int t    = threadIdx.x;
    const int lane = t & 63;
    const int w    = t >> 6;

    __shared__ float4 sp[NPTS];                      // 128 KB
    __shared__ __align__(16) u64 keys[2][8];

    if (bid < NBATCH) {
        // ---------------- FPS producer (r11 body + per-iter publish) --------
        const int b = bid;
        const float* base = pc + (size_t)b * NPTS * 6;

        float px[16], py[16], pz[16], dmin[16];
#pragma unroll
        for (int j = 0; j < 16; ++j) {
            const int p = t * 16 + j;
            const float x = base[p * 6 + 0];
            const float y = base[p * 6 + 1];
            const float z = base[p * 6 + 2];
            px[j] = x; py[j] = y; pz[j] = z;
            sp[p] = make_float4(x, y, z, 0.0f);
            dmin[j] = BIGF;
        }
        __syncthreads();

        int last = 0;
        for (int k = 0; k < NGROUP; ++k) {
            if (t == 0)
                __hip_atomic_store(rep + b * NGROUP + k, last,
                                   __ATOMIC_RELAXED, __HIP_MEMORY_SCOPE_AGENT);
            if (k == NGROUP - 1) break;

            const float4 L = sp[last];               // one ds_read_b128, broadcast

            float bv = -1.0f;
            int   bi = 0;
#pragma unroll
            for (int j = 0; j < 16; ++j) {
                const float dx = __fsub_rn(px[j], L.x);
                const float dy = __fsub_rn(py[j], L.y);
                const float dz = __fsub_rn(pz[j], L.z);
                // ((dx^2 + dy^2) + dz^2), no FMA -> matches numpy fp32 (verified)
                const float d = __fadd_rn(__fadd_rn(__fmul_rn(dx, dx),
                                                    __fmul_rn(dy, dy)),
                                          __fmul_rn(dz, dz));
                const float dm = fminf(dmin[j], d);
                dmin[j] = dm;
                if (dm > bv) { bv = dm; bi = t * 16 + j; }   // strict > keeps lowest idx
            }

            u64 key = ((u64)__float_as_uint(bv) << 13) | (unsigned)(8191 - bi);
            key = dpp_max_u64<0x111>(key);   // row_shr:1
            key = dpp_max_u64<0x112>(key);   // row_shr:2
            key = dpp_max_u64<0x114>(key);   // row_shr:4
            key = dpp_max_u64<0x118>(key);   // row_shr:8
            key = dpp_max_u64<0x142>(key);   // row_bcast:15
            key = dpp_max_u64<0x143>(key);   // row_bcast:31 -> lane 63 = wave max

            const int buf = k & 1;                   // parity dbuf -> 1 barrier/iter
            if (lane == 63) keys[buf][w] = key;
            __syncthreads();

            const ulonglong2* kp = (const ulonglong2*)keys[buf];   // 4x ds_read_b128
            const ulonglong2 k0 = kp[0], k1 = kp[1], k2 = kp[2], k3 = kp[3];
            const u64 best = umax64(umax64(umax64(k0.x, k0.y), umax64(k1.x, k1.y)),
                                    umax64(umax64(k2.x, k2.y), umax64(k3.x, k3.y)));
            last = 8191 - (int)(best & 0x1FFFull);
        }
    } else {
        // ---------------- KNN consumers (XCD-co-located with producer) ------
        const int x    = bid & 7;                    // this block's XCD
        const int slot = (bid >> 3) - 2;             // 0..13
        const int b    = x + 8 * (slot / KBLK);      // batch on the SAME XCD
        const int j    = slot % KBLK;                // block-in-batch 0..6
        const int m0   = j * 8 + w;                  // wave's first query
        const int stride = KBLK * 8;                 // 56 wave-slots per batch

        const float* base = pc + (size_t)b * NPTS * 6;

        // stage the whole batch's xyz into this block's LDS (idle time:
        // happens before fps publishes anything)
#pragma unroll
        for (int jj = 0; jj < NPTS / 512; ++jj) {
            const int p = jj * 512 + t;
            sp[p] = make_float4(base[p * 6 + 0], base[p * 6 + 1],
                                base[p * 6 + 2], 0.0f);
        }
        __syncthreads();

        for (int m = m0; m < NGROUP; m += stride) {
            const int q = b * NGROUP + m;
            int rv;
            for (;;) {
                rv = __hip_atomic_load(rep + q, __ATOMIC_RELAXED,
                                       __HIP_MEMORY_SCOPE_AGENT);
                if (rv >= 0) break;
                __builtin_amdgcn_s_sleep(127);
            }
            knn_one(base, sp, out, q, rv, lane);
        }
    }
}

extern "C" void kernel_launch(void* const* d_in, const int* in_sizes, int n_in,
                              void* d_out, int out_size, void* d_ws, size_t ws_size,
                              hipStream_t stream) {
    const float* pc  = (const float*)d_in[0];
    float*       out = (float*)d_out;
    int*         rep = (int*)d_ws;                   // 32 KB

    // rep = -1 sentinels (0xFF bytes) — stream op, graph-capture-safe
    hipMemsetAsync(rep, 0xFF, (size_t)NBATCH * NGROUP * sizeof(int), stream);

    fused_kernel<<<NBATCH + NBATCH * KBLK, 512, 0, stream>>>(pc, rep, out);
}

// Round 22
// 573.482 us; speedup vs baseline: 1.0277x; 1.0114x over previous
//
#include <hip/hip_runtime.h>

#define NPTS   8192
#define NBATCH 16
#define NGROUP 512
#define GSIZE  32
#define BIGF   1e10f
#define KBLK   7          // consumer blocks per batch (r19 optimum)

typedef unsigned long long u64;

// DPP max on a packed u64 key (round-7 proven).
template <int CTRL>
__device__ __forceinline__ u64 dpp_max_u64(u64 k) {
    const unsigned lo  = (unsigned)k;
    const unsigned hi  = (unsigned)(k >> 32);
    const unsigned slo = (unsigned)__builtin_amdgcn_update_dpp(0, (int)lo, CTRL, 0xF, 0xF, true);
    const unsigned shi = (unsigned)__builtin_amdgcn_update_dpp(0, (int)hi, CTRL, 0xF, 0xF, true);
    const u64 s = ((u64)shi << 32) | slo;
    return s > k ? s : k;
}

__device__ __forceinline__ u64 umax64(u64 a, u64 b) { return a > b ? a : b; }

// wave-uniform 64-bit readlane (SALU path, no LDS pipe)
__device__ __forceinline__ u64 rdlane64(u64 v, int l) {
    const unsigned lo = (unsigned)__builtin_amdgcn_readlane((int)(unsigned)v, l);
    const unsigned hi = (unsigned)__builtin_amdgcn_readlane((int)(unsigned)(v >> 32), l);
    return ((u64)hi << 32) | lo;
}

// ---------------------------------------------------------------------------
// knn scan for ONE query — r11 machinery (u64 keys = f64 bit order, readlane
// broadcasts, 2 points/lane/iter, lane-distributed sorted top-32) reading the
// block's LDS copy of the batch xyz. Bit-identical keys/order to r11.
// ---------------------------------------------------------------------------
__device__ __forceinline__ void knn_one(const float* __restrict__ base,
                                        const float4* sp,
                                        float* __restrict__ out,
                                        const int q, const int r, const int lane) {
    const float4 Q = sp[r];
    const float qxf = Q.x, qyf = Q.y, qzf = Q.z;
    const double qx = (double)qxf, qy = (double)qyf, qz = (double)qzf;

    const u64 INFB = 0x7ff0000000000000ull;
    u64 vk = INFB;  int vi = 0x7fffffff;
    u64 tauk = INFB;

    for (int i = 0; i < NPTS / 128; ++i) {
        const int p0 = i * 128 + lane;
        const float4 T0 = sp[p0];
        const float4 T1 = sp[p0 + 64];

        const double dx0 = qx - (double)T0.x;
        const double dy0 = qy - (double)T0.y;
        const double dz0 = qz - (double)T0.z;
        const u64 kd0 = __double_as_longlong(dx0 * dx0 + dy0 * dy0 + dz0 * dz0);
        const double dx1 = qx - (double)T1.x;
        const double dy1 = qy - (double)T1.y;
        const double dz1 = qz - (double)T1.z;
        const u64 kd1 = __double_as_longlong(dx1 * dx1 + dy1 * dy1 + dz1 * dz1);

        u64 m0 = __ballot(kd0 < tauk);
        const u64 m1pre = __ballot(kd1 < tauk);

        if (m0 | m1pre) {
            while (m0) {
                const int l = __ffsll(m0) - 1;
                m0 &= m0 - 1;
                const u64 xk = rdlane64(kd0, l);
                const int xi = i * 128 + l;
                const u64 pk = __shfl_up(vk, 1);
                const int pv = __shfl_up(vi, 1);
                const bool ltp = (lane > 0) && (xk < pk);
                const bool ltc = xk < vk;
                vk = ltp ? pk : (ltc ? xk : vk);
                vi = ltp ? pv : (ltc ? xi : vi);
            }
            tauk = rdlane64(vk, 31);
            u64 m1 = m1pre;
            while (m1) {
                const int l = __ffsll(m1) - 1;
                m1 &= m1 - 1;
                const u64 xk = rdlane64(kd1, l);
                if (xk < tauk) {
                    const int xi = i * 128 + 64 + l;
                    const u64 pk = __shfl_up(vk, 1);
                    const int pv = __shfl_up(vi, 1);
                    const bool ltp = (lane > 0) && (xk < pk);
                    const bool ltc = xk < vk;
                    vk = ltp ? pk : (ltc ? xk : vk);
                    vi = ltp ? pv : (ltc ? xi : vi);
                }
            }
            tauk = rdlane64(vk, 31);
        }
    }

    const size_t NBH = (size_t)NBATCH * NGROUP * GSIZE * 6;
    const size_t CEN = (size_t)NBATCH * NGROUP * 6;

    if (lane == 0) {
#pragma unroll
        for (int c = 0; c < 6; ++c)
            out[NBH + (size_t)q * 6 + c] = base[r * 6 + c];
    }
    if (lane < GSIZE) {
        const int n = vi;
        out[NBH + CEN + (size_t)q * GSIZE + lane] = (float)n;

        const float* np_ = base + (size_t)n * 6;
        const size_t o = ((size_t)q * GSIZE + lane) * 6;
        out[o + 0] = __fsub_rn(np_[0], qxf);
        out[o + 1] = __fsub_rn(np_[1], qyf);
        out[o + 2] = __fsub_rn(np_[2], qzf);
        out[o + 3] = np_[3];
        out[o + 4] = np_[4];
        out[o + 5] = np_[5];
    }
}

// ---------------------------------------------------------------------------
// Fused producer/consumer — ROUND-19 VERBATIM (571.85us, session best).
// Falsification ledger for the residual ~34us producer tax vs standalone fps:
// read-BW (r16), acquire-coherence (r17), poll-rate (r18), store-batching
// (r20), XCD-co-location (r21) all falsified; partial confirmation of
// chip-activity/clock via r19's CU halving (-11us). Structure:
//  blocks 0..15   : fps producer per batch (r11 body, proven floor 543us
//                   standalone), rep[b][k] relaxed agent store per iter.
//  blocks 16..127 : 7 consumer blocks/batch; stage batch xyz to own LDS,
//                   relaxed-poll rep[q] with s_sleep(127), scan from LDS.
//  1 block/CU (129KB LDS) -> all 128 co-resident, deadlock-free by capacity.
// ---------------------------------------------------------------------------
__global__ __launch_bounds__(512) void fused_kernel(const float* __restrict__ pc,
                                                    int* __restrict__ rep,
                                                    float* __restrict__ out) {
    const int bid  = blockIdx.x;
    const int t    = threadIdx.x;
    const int lane = t & 63;
    const int w    = t >> 6;

    __shared__ float4 sp[NPTS];                      // 128 KB
    __shared__ __align__(16) u64 keys[2][8];

    if (bid < NBATCH) {
        // ---------------- FPS producer (r11 body + per-iter publish) --------
        const int b = bid;
        const float* base = pc + (size_t)b * NPTS * 6;

        float px[16], py[16], pz[16], dmin[16];
#pragma unroll
        for (int j = 0; j < 16; ++j) {
            const int p = t * 16 + j;
            const float x = base[p * 6 + 0];
            const float y = base[p * 6 + 1];
            const float z = base[p * 6 + 2];
            px[j] = x; py[j] = y; pz[j] = z;
            sp[p] = make_float4(x, y, z, 0.0f);
            dmin[j] = BIGF;
        }
        __syncthreads();

        int last = 0;
        for (int k = 0; k < NGROUP; ++k) {
            if (t == 0)
                __hip_atomic_store(rep + b * NGROUP + k, last,
                                   __ATOMIC_RELAXED, __HIP_MEMORY_SCOPE_AGENT);
            if (k == NGROUP - 1) break;

            const float4 L = sp[last];               // one ds_read_b128, broadcast

            float bv = -1.0f;
            int   bi = 0;
#pragma unroll
            for (int j = 0; j < 16; ++j) {
                const float dx = __fsub_rn(px[j], L.x);
                const float dy = __fsub_rn(py[j], L.y);
                const float dz = __fsub_rn(pz[j], L.z);
                // ((dx^2 + dy^2) + dz^2), no FMA -> matches numpy fp32 (verified)
                const float d = __fadd_rn(__fadd_rn(__fmul_rn(dx, dx),
                                                    __fmul_rn(dy, dy)),
                                          __fmul_rn(dz, dz));
                const float dm = fminf(dmin[j], d);
                dmin[j] = dm;
                if (dm > bv) { bv = dm; bi = t * 16 + j; }   // strict > keeps lowest idx
            }

            u64 key = ((u64)__float_as_uint(bv) << 13) | (unsigned)(8191 - bi);
            key = dpp_max_u64<0x111>(key);   // row_shr:1
            key = dpp_max_u64<0x112>(key);   // row_shr:2
            key = dpp_max_u64<0x114>(key);   // row_shr:4
            key = dpp_max_u64<0x118>(key);   // row_shr:8
            key = dpp_max_u64<0x142>(key);   // row_bcast:15
            key = dpp_max_u64<0x143>(key);   // row_bcast:31 -> lane 63 = wave max

            const int buf = k & 1;                   // parity dbuf -> 1 barrier/iter
            if (lane == 63) keys[buf][w] = key;
            __syncthreads();

            const ulonglong2* kp = (const ulonglong2*)keys[buf];   // 4x ds_read_b128
            const ulonglong2 k0 = kp[0], k1 = kp[1], k2 = kp[2], k3 = kp[3];
            const u64 best = umax64(umax64(umax64(k0.x, k0.y), umax64(k1.x, k1.y)),
                                    umax64(umax64(k2.x, k2.y), umax64(k3.x, k3.y)));
            last = 8191 - (int)(best & 0x1FFFull);
        }
    } else {
        // ---------------- KNN consumers -------------------------------------
        const int kb = bid - NBATCH;                 // 0..NBATCH*KBLK-1
        const int b  = kb / KBLK;                    // batch
        const int j  = kb % KBLK;                    // block-in-batch
        const int m0 = j * 8 + w;                    // wave's first query
        const int stride = KBLK * 8;                 // 56 wave-slots per batch

        const float* base = pc + (size_t)b * NPTS * 6;

        // stage the whole batch's xyz into this block's LDS (idle time:
        // happens before fps publishes anything)
#pragma unroll
        for (int jj = 0; jj < NPTS / 512; ++jj) {
            const int p = jj * 512 + t;
            sp[p] = make_float4(base[p * 6 + 0], base[p * 6 + 1],
                                base[p * 6 + 2], 0.0f);
        }
        __syncthreads();

        for (int m = m0; m < NGROUP; m += stride) {
            const int q = b * NGROUP + m;
            int rv;
            for (;;) {
                rv = __hip_atomic_load(rep + q, __ATOMIC_RELAXED,
                                       __HIP_MEMORY_SCOPE_AGENT);
                if (rv >= 0) break;
                __builtin_amdgcn_s_sleep(127);
            }
            knn_one(base, sp, out, q, rv, lane);
        }
    }
}

extern "C" void kernel_launch(void* const* d_in, const int* in_sizes, int n_in,
                              void* d_out, int out_size, void* d_ws, size_t ws_size,
                              hipStream_t stream) {
    const float* pc  = (const float*)d_in[0];
    float*       out = (float*)d_out;
    int*         rep = (int*)d_ws;                   // 32 KB

    // rep = -1 sentinels (0xFF bytes) — stream op, graph-capture-safe
    hipMemsetAsync(rep, 0xFF, (size_t)NBATCH * NGROUP * sizeof(int), stream);

    fused_kernel<<<NBATCH + NBATCH * KBLK, 512, 0, stream>>>(pc, rep, out);
}